// Round 11
// baseline (165.495 us; speedup 1.0000x reference)
//
#include <hip/hip_runtime.h>
#include <hip/hip_bf16.h>
#include <math.h>

// ---------------- problem constants ----------------
#define M 8192
#define N 16384
#define D 64
#define ZC 58.81206612509905f        // 32*log(2*pi), h=1
#define B0 24.0f                     // exp2-domain bias (headroom; u<=0)
#define LOG2E 1.4426950408889634f
#define HL2E 0.7213475204444817f     // 0.5*log2(e)
#define LN2 0.6931471805599453f

#define PCH 32
#define NCHK (N / PCH)               // 512 train cols per block
#define RB 256                       // test rows per block (64 per wave)
#define NTILES (NCHK / 32)           // 16 wave-private 32-col tiles

typedef short v8bf __attribute__((ext_vector_type(8)));   // 8 bf16 (4 VGPRs)
typedef float v16f __attribute__((ext_vector_type(16)));

// ws layout (bytes)
#define B_AU2  0                        // 8192 f32  (32 KB)
#define B_LW2  32768                    // 16384 f32 (64 KB)
#define B_PART 98304                    // 32*8192 f32 (1 MB), [chunk][m]
#define B_TB   1146880                  // 8192*64 bf16 (1 MB)
#define B_TR   2195456                  // 16384*64 bf16 (2 MB)

// Fused prep: blocks 0..255 convert testX -> bf16(log2e*x) + au2;
// blocks 256..767 convert trainX -> bf16 + lw2 = log2(w) - hl2e*r2 + B0.
__global__ __launch_bounds__(256) void gk_prep(const float* __restrict__ testX,
                                               const float* __restrict__ trainX,
                                               const float* __restrict__ sw,
                                               __hip_bfloat16* __restrict__ tb,
                                               __hip_bfloat16* __restrict__ rb,
                                               float* __restrict__ au2,
                                               float* __restrict__ lw2) {
    const int tid = threadIdx.x;
    const int e = tid & 7;
    if (blockIdx.x < M / 32) {
        const int row = blockIdx.x * 32 + (tid >> 3);
        const float4* p = reinterpret_cast<const float4*>(testX + (size_t)row * D + e * 8);
        float4 v0 = p[0], v1 = p[1];
        float t2 = v0.x * v0.x + v0.y * v0.y + v0.z * v0.z + v0.w * v0.w
                 + v1.x * v1.x + v1.y * v1.y + v1.z * v1.z + v1.w * v1.w;
        t2 += __shfl_xor(t2, 1, 64);
        t2 += __shfl_xor(t2, 2, 64);
        t2 += __shfl_xor(t2, 4, 64);
        if (e == 0) au2[row] = -HL2E * t2;
        union { __hip_bfloat16 h[8]; uint4 u; } cv;
        cv.h[0] = __float2bfloat16(v0.x * LOG2E);
        cv.h[1] = __float2bfloat16(v0.y * LOG2E);
        cv.h[2] = __float2bfloat16(v0.z * LOG2E);
        cv.h[3] = __float2bfloat16(v0.w * LOG2E);
        cv.h[4] = __float2bfloat16(v1.x * LOG2E);
        cv.h[5] = __float2bfloat16(v1.y * LOG2E);
        cv.h[6] = __float2bfloat16(v1.z * LOG2E);
        cv.h[7] = __float2bfloat16(v1.w * LOG2E);
        *reinterpret_cast<uint4*>(tb + (size_t)row * D + e * 8) = cv.u;
    } else {
        const int row = (blockIdx.x - M / 32) * 32 + (tid >> 3);
        const float4* p = reinterpret_cast<const float4*>(trainX + (size_t)row * D + e * 8);
        float4 v0 = p[0], v1 = p[1];
        float r2 = v0.x * v0.x + v0.y * v0.y + v0.z * v0.z + v0.w * v0.w
                 + v1.x * v1.x + v1.y * v1.y + v1.z * v1.z + v1.w * v1.w;
        r2 += __shfl_xor(r2, 1, 64);
        r2 += __shfl_xor(r2, 2, 64);
        r2 += __shfl_xor(r2, 4, 64);
        if (e == 0) lw2[row] = __builtin_amdgcn_logf(sw[row]) - HL2E * r2 + B0;
        union { __hip_bfloat16 h[8]; uint4 u; } cv;
        cv.h[0] = __float2bfloat16(v0.x);
        cv.h[1] = __float2bfloat16(v0.y);
        cv.h[2] = __float2bfloat16(v0.z);
        cv.h[3] = __float2bfloat16(v0.w);
        cv.h[4] = __float2bfloat16(v1.x);
        cv.h[5] = __float2bfloat16(v1.y);
        cv.h[6] = __float2bfloat16(v1.z);
        cv.h[7] = __float2bfloat16(v1.w);
        *reinterpret_cast<uint4*>(rb + (size_t)row * D + e * 8) = cv.u;
    }
}

// Direct global->LDS DMA, 16 B/lane (no VGPR round-trip => nothing to spill).
__device__ __forceinline__ void dma16(const void* g, void* l) {
    __builtin_amdgcn_global_load_lds(
        (const __attribute__((address_space(1))) unsigned int*)g,
        (__attribute__((address_space(3))) unsigned int*)l, 16, 0, 0);
}

// Stage one wave-private 32x64 bf16 B-tile (4 KB, 4 DMAs): call i covers B
// rows i*8..i*8+7: lane L fetches row i*8+(L&7), k-chunk L>>3, landing at
// dst+i*1024+L*16 => LDS(rr,kc) = (rr>>3)*1024 + kc*128 + (rr&7)*16.
__device__ __forceinline__ void dma_tile32(const __hip_bfloat16* tr, int nt,
                                           char* dst, int lane) {
#pragma unroll
    for (int i = 0; i < 4; ++i) {
        const __hip_bfloat16* gp =
            tr + (size_t)(nt + i * 8 + (lane & 7)) * D + (lane >> 3) * 8;
        dma16(gp, dst + i * 1024);
    }
}

// Compute one 64(rows) x 32(cols) wave-private tile: shared bf frags feed
// two m-subtile MFMA chains; bias lw2 in the C operand; epilogue exp2+add.
__device__ __forceinline__ void compute_tile32(const char* myb, float lwv,
                                               const v8bf af[2][4],
                                               float srun[2][16], int c, int h) {
    v8bf bf[4];
#pragma unroll
    for (int t = 0; t < 4; ++t)
        bf[t] = *reinterpret_cast<const v8bf*>(
            myb + (c >> 3) * 1024 + (2 * t + h) * 128 + (c & 7) * 16);
    v16f a0, a1;
#pragma unroll
    for (int r = 0; r < 16; ++r) { a0[r] = lwv; a1[r] = lwv; }
#pragma unroll
    for (int t = 0; t < 4; ++t)
        a0 = __builtin_amdgcn_mfma_f32_32x32x16_bf16(af[0][t], bf[t], a0, 0, 0, 0);
#pragma unroll
    for (int t = 0; t < 4; ++t)
        a1 = __builtin_amdgcn_mfma_f32_32x32x16_bf16(af[1][t], bf[t], a1, 0, 0, 0);
#pragma unroll
    for (int r = 0; r < 16; ++r) {
        srun[0][r] += __builtin_amdgcn_exp2f(a0[r]);
        srun[1][r] += __builtin_amdgcn_exp2f(a1[r]);
    }
}

// Main: 256 test rows x 512 train cols per block; grid 1024 = EXACTLY
// 4 blocks/CU (no tail quantization). BARRIER-FREE: each wave owns 64 rows
// x all 512 cols, stages its own 32-col B-tiles into wave-private LDS dbuf
// via global_load_lds, and self-syncs with fine s_waitcnt vmcnt(5) (tile t
// drained, tile t+1 in flight -- the cp.async.wait_group pattern). Zero
// __syncthreads in the kernel; epilogue reduces via shfl_xor in-register.
__global__ __launch_bounds__(256, 4) void gk_main(const __hip_bfloat16* __restrict__ ta,
                                                  const __hip_bfloat16* __restrict__ tr,
                                                  const float* __restrict__ lw2,
                                                  float* __restrict__ part) {
    __shared__ __align__(16) char smem[32768];   // 4 waves x (2 x 4 KB dbuf)
    const int tid = threadIdx.x;
    const int w = tid >> 6;
    const int lane = tid & 63;
    const int c = lane & 31;
    const int h = lane >> 5;

    // XCD swizzle: xcd = bid&7 owns chunks 4x..4x+3 (L2-local B slice)
    const int bid = blockIdx.x;
    const int chunk = (bid & 7) * 4 + ((bid >> 3) & 3);
    const int m0 = (bid >> 5) * RB;
    const int n0 = chunk * NCHK;

    char* const myb0 = smem + w * 8192;
    char* const myb1 = myb0 + 4096;

    // A fragments: this wave's 64 rows (2 m-subtiles), straight from global
    const __hip_bfloat16* ar = ta + (size_t)(m0 + w * 64 + c) * D;
    v8bf af[2][4];
#pragma unroll
    for (int t = 0; t < 4; ++t) {
        af[0][t] = *reinterpret_cast<const v8bf*>(ar + (2 * t + h) * 8);
        af[1][t] = *reinterpret_cast<const v8bf*>(ar + 32 * D + (2 * t + h) * 8);
    }

    // prologue: 2 tiles in flight (5 vmem ops each: 4 DMA + 1 lw load)
    dma_tile32(tr, n0, myb0, lane);
    float lw0 = lw2[n0 + c];
    dma_tile32(tr, n0 + 32, myb1, lane);
    float lw1 = lw2[n0 + 32 + c];

    float srun[2][16];
#pragma unroll
    for (int ms = 0; ms < 2; ++ms)
#pragma unroll
        for (int r = 0; r < 16; ++r) srun[ms][r] = 0.f;

#pragma unroll
    for (int t = 0; t < NTILES; ++t) {
        // wait for tile t's 5 vmem ops; tile t+1's 5 stay in flight
        if (t < NTILES - 2) __builtin_amdgcn_s_waitcnt(0x0F75);  // vmcnt(5)
        else                __builtin_amdgcn_s_waitcnt(0x0F70);  // vmcnt(0)

        const char* myb = (t & 1) ? myb1 : myb0;
        const float lwv = (t & 1) ? lw1 : lw0;
        compute_tile32(myb, lwv, af, srun, c, h);

        // refill the buffer just consumed with tile t+2
        if (t + 2 < NTILES) {
            const int nt2 = n0 + (t + 2) * 32;
            char* dst = (t & 1) ? myb1 : myb0;
            dma_tile32(tr, nt2, dst, lane);
            if (t & 1) lw1 = lw2[nt2 + c];
            else       lw0 = lw2[nt2 + c];
        }
    }

    // ---- wave-level reduction over the 32 col-lanes (shfl, no LDS) ----
#pragma unroll
    for (int ms = 0; ms < 2; ++ms)
#pragma unroll
        for (int r = 0; r < 16; ++r) {
            float v = srun[ms][r];
            v += __shfl_xor(v, 1, 64);
            v += __shfl_xor(v, 2, 64);
            v += __shfl_xor(v, 4, 64);
            v += __shfl_xor(v, 8, 64);
            v += __shfl_xor(v, 16, 64);
            srun[ms][r] = v;
        }
    if (c == 0) {
#pragma unroll
        for (int ms = 0; ms < 2; ++ms)
#pragma unroll
            for (int r = 0; r < 16; ++r) {
                const int row = w * 64 + ms * 32 + (r & 3) + 8 * (r >> 2) + 4 * h;
                part[(size_t)chunk * M + m0 + row] = srun[ms][r];
            }
    }
}

__global__ __launch_bounds__(256) void gk_merge(const float* __restrict__ part,
                                                const float* __restrict__ au2,
                                                const float* __restrict__ sw,
                                                float* __restrict__ out) {
    __shared__ float red[256];
    const int tid = threadIdx.x;
    // W = sum(sw), recomputed per block (64 KB, L2-resident, fully parallel)
    float s = 0.f;
    const float4* p4 = reinterpret_cast<const float4*>(sw);
    for (int i = tid; i < N / 4; i += 256) {
        float4 v = p4[i];
        s += v.x + v.y + v.z + v.w;
    }
    red[tid] = s;
    __syncthreads();
    for (int off = 128; off > 0; off >>= 1) {
        if (tid < off) red[tid] += red[tid + off];
        __syncthreads();
    }
    const float W = red[0];

    const int r = blockIdx.x * 256 + tid;
    float G = 0.f;
#pragma unroll
    for (int p = 0; p < PCH; ++p) G += part[(size_t)p * M + r];
    out[r] = LN2 * (au2[r] + __builtin_amdgcn_logf(fmaxf(G, 1e-30f)) - B0
                   - __builtin_amdgcn_logf(W)) - ZC;
}

extern "C" void kernel_launch(void* const* d_in, const int* in_sizes, int n_in,
                              void* d_out, int out_size, void* d_ws, size_t ws_size,
                              hipStream_t stream) {
    const float* testX  = (const float*)d_in[0];   // [8192, 64]
    const float* trainX = (const float*)d_in[1];   // [16384, 64]
    const float* sw     = (const float*)d_in[2];   // [16384]
    float* out = (float*)d_out;                    // [8192]
    char* wsb = (char*)d_ws;

    float* au2  = (float*)(wsb + B_AU2);
    float* lw2  = (float*)(wsb + B_LW2);
    float* part = (float*)(wsb + B_PART);
    __hip_bfloat16* tb = (__hip_bfloat16*)(wsb + B_TB);
    __hip_bfloat16* rb = (__hip_bfloat16*)(wsb + B_TR);

    gk_prep<<<M / 32 + N / 32, 256, 0, stream>>>(testX, trainX, sw, tb, rb, au2, lw2);
    gk_main<<<(M / RB) * PCH, 256, 0, stream>>>(tb, rb, lw2, part);
    gk_merge<<<M / 256, 256, 0, stream>>>(part, au2, sw, out);
}

// Round 12
// 95.682 us; speedup vs baseline: 1.7296x; 1.7296x over previous
//
#include <hip/hip_runtime.h>
#include <hip/hip_bf16.h>
#include <math.h>

// ---------------- problem constants ----------------
#define M 8192
#define N 16384
#define D 64
#define ZC 58.81206612509905f        // 32*log(2*pi), h=1
#define B0 24.0f                     // exp2-domain bias (headroom; u<=0)
#define LOG2E 1.4426950408889634f
#define HL2E 0.7213475204444817f     // 0.5*log2(e)
#define LN2 0.6931471805599453f

#define PCH 32
#define NCHK (N / PCH)               // 512 train cols per block

typedef short v8bf __attribute__((ext_vector_type(8)));   // 8 bf16 (4 VGPRs)
typedef float v16f __attribute__((ext_vector_type(16)));

// ws layout (bytes)
#define B_AU2  0                        // 8192 f32  (32 KB)
#define B_LW2  32768                    // 16384 f32 (64 KB)
#define B_PART 98304                    // 32*8192 f32 (1 MB), [chunk][m]
#define B_TB   1146880                  // 8192*64 bf16 (1 MB)
#define B_TR   2195456                  // 16384*64 bf16 (2 MB)

// Fused prep: blocks 0..255 convert testX -> bf16(log2e*x) + au2;
// blocks 256..767 convert trainX -> bf16 + lw2 = log2(w) - hl2e*r2 + B0.
__global__ __launch_bounds__(256) void gk_prep(const float* __restrict__ testX,
                                               const float* __restrict__ trainX,
                                               const float* __restrict__ sw,
                                               __hip_bfloat16* __restrict__ tb,
                                               __hip_bfloat16* __restrict__ rb,
                                               float* __restrict__ au2,
                                               float* __restrict__ lw2) {
    const int tid = threadIdx.x;
    const int e = tid & 7;
    if (blockIdx.x < M / 32) {
        const int row = blockIdx.x * 32 + (tid >> 3);
        const float4* p = reinterpret_cast<const float4*>(testX + (size_t)row * D + e * 8);
        float4 v0 = p[0], v1 = p[1];
        float t2 = v0.x * v0.x + v0.y * v0.y + v0.z * v0.z + v0.w * v0.w
                 + v1.x * v1.x + v1.y * v1.y + v1.z * v1.z + v1.w * v1.w;
        t2 += __shfl_xor(t2, 1, 64);
        t2 += __shfl_xor(t2, 2, 64);
        t2 += __shfl_xor(t2, 4, 64);
        if (e == 0) au2[row] = -HL2E * t2;
        union { __hip_bfloat16 h[8]; uint4 u; } cv;
        cv.h[0] = __float2bfloat16(v0.x * LOG2E);
        cv.h[1] = __float2bfloat16(v0.y * LOG2E);
        cv.h[2] = __float2bfloat16(v0.z * LOG2E);
        cv.h[3] = __float2bfloat16(v0.w * LOG2E);
        cv.h[4] = __float2bfloat16(v1.x * LOG2E);
        cv.h[5] = __float2bfloat16(v1.y * LOG2E);
        cv.h[6] = __float2bfloat16(v1.z * LOG2E);
        cv.h[7] = __float2bfloat16(v1.w * LOG2E);
        *reinterpret_cast<uint4*>(tb + (size_t)row * D + e * 8) = cv.u;
    } else {
        const int row = (blockIdx.x - M / 32) * 32 + (tid >> 3);
        const float4* p = reinterpret_cast<const float4*>(trainX + (size_t)row * D + e * 8);
        float4 v0 = p[0], v1 = p[1];
        float r2 = v0.x * v0.x + v0.y * v0.y + v0.z * v0.z + v0.w * v0.w
                 + v1.x * v1.x + v1.y * v1.y + v1.z * v1.z + v1.w * v1.w;
        r2 += __shfl_xor(r2, 1, 64);
        r2 += __shfl_xor(r2, 2, 64);
        r2 += __shfl_xor(r2, 4, 64);
        if (e == 0) lw2[row] = __builtin_amdgcn_logf(sw[row]) - HL2E * r2 + B0;
        union { __hip_bfloat16 h[8]; uint4 u; } cv;
        cv.h[0] = __float2bfloat16(v0.x);
        cv.h[1] = __float2bfloat16(v0.y);
        cv.h[2] = __float2bfloat16(v0.z);
        cv.h[3] = __float2bfloat16(v0.w);
        cv.h[4] = __float2bfloat16(v1.x);
        cv.h[5] = __float2bfloat16(v1.y);
        cv.h[6] = __float2bfloat16(v1.z);
        cv.h[7] = __float2bfloat16(v1.w);
        *reinterpret_cast<uint4*>(rb + (size_t)row * D + e * 8) = cv.u;
    }
}

// Direct global->LDS DMA, 16 B/lane (no VGPR round-trip => nothing to spill).
__device__ __forceinline__ void dma16(const void* g, void* l) {
    __builtin_amdgcn_global_load_lds(
        (const __attribute__((address_space(1))) unsigned int*)g,
        (__attribute__((address_space(3))) unsigned int*)l, 16, 0, 0);
}

// Stage one 64x64 bf16 B-tile (8 KB): wave w issues 2 DMAs; call g covers
// rows g*8..g*8+7: lane L fetches row g*8+(L&7), k-chunk (L>>3), landing at
// base+g*1024+L*16 => LDS(rr,kc) = (rr>>3)*1024 + kc*128 + (rr&7)*16.
__device__ __forceinline__ void dma_tile(const __hip_bfloat16* tr, int nt,
                                         char* Bsb, int w, int lane) {
#pragma unroll
    for (int i = 0; i < 2; ++i) {
        const int g = w * 2 + i;
        const __hip_bfloat16* gp =
            tr + (size_t)(nt + g * 8 + (lane & 7)) * D + (lane >> 3) * 8;
        dma16(gp, Bsb + g * 1024);
    }
}

// Compute one 128(rows) x 64(cols) tile from LDS. lwa/lwb are this lane's
// bias values for col-subtiles 0/1, loaded a full tile EARLY (alongside the
// DMA) so tile start goes ds_read -> MFMA with no dependent global load.
__device__ __forceinline__ void compute_tile(const char* Bs, float lwa, float lwb,
                                             const v8bf af[4], float srun[16],
                                             int c, int h) {
#pragma unroll
    for (int s = 0; s < 2; ++s) {
        const float lwv = s ? lwb : lwa;
        v16f acc;
#pragma unroll
        for (int r = 0; r < 16; ++r) acc[r] = lwv;
#pragma unroll
        for (int t = 0; t < 4; ++t) {
            const v8bf bf = *reinterpret_cast<const v8bf*>(
                Bs + (s * 4 + (c >> 3)) * 1024 + (2 * t + h) * 128 + (c & 7) * 16);
            acc = __builtin_amdgcn_mfma_f32_32x32x16_bf16(af[t], bf, acc, 0, 0, 0);
        }
#pragma unroll
        for (int r = 0; r < 16; ++r)
            srun[r] += __builtin_amdgcn_exp2f(acc[r]);
    }
}

// Main: 128 test rows x 512 train cols per block (grid 2048). 8 KB dbuf
// DMA pipeline (8 tiles, 1 barrier each); LDS 16.9 KB; (256,6) -> 6
// blocks/CU (r10's proven shape). The lw2 bias loads ride with the
// previous tile's DMA (drained by the same pre-barrier vmcnt(0)), so the
// post-barrier critical path has no dependent global load.
__global__ __launch_bounds__(256, 6) void gk_main(const __hip_bfloat16* __restrict__ ta,
                                                  const __hip_bfloat16* __restrict__ tr,
                                                  const float* __restrict__ lw2,
                                                  float* __restrict__ part) {
    __shared__ __align__(16) char smem[16896];   // dbuf 2x8K; red 128x33 f32 reuses
    const int tid = threadIdx.x;
    const int w = tid >> 6;
    const int lane = tid & 63;
    const int c = lane & 31;
    const int h = lane >> 5;

    // XCD swizzle: xcd = bid&7 owns chunks 4x..4x+3 (2048 train rows L2-local)
    const int bid = blockIdx.x;
    const int xcd = bid & 7;
    const int j = bid >> 3;
    const int chunk = xcd * 4 + (j & 3);
    const int m0 = (j >> 2) * 128;
    const int n0 = chunk * NCHK;

    char* const Bs0 = smem;
    char* const Bs1 = smem + 8192;

    // kick off tile 0 DMA + tile 0 bias loads, then A fragments while they fly
    dma_tile(tr, n0, Bs0, w, lane);
    float lwa0 = lw2[n0 + c], lwb0 = lw2[n0 + 32 + c];

    const __hip_bfloat16* arow = ta + (size_t)(m0 + w * 32 + c) * D;
    v8bf af[4];
#pragma unroll
    for (int t = 0; t < 4; ++t)
        af[t] = *reinterpret_cast<const v8bf*>(arow + (2 * t + h) * 8);

    float srun[16];
#pragma unroll
    for (int r = 0; r < 16; ++r) srun[r] = 0.f;

    float lwa1, lwb1;
    __syncthreads();                                   // tile0 staged
    dma_tile(tr, n0 + 64, Bs1, w, lane);
    lwa1 = lw2[n0 + 64 + c]; lwb1 = lw2[n0 + 96 + c];
    compute_tile(Bs0, lwa0, lwb0, af, srun, c, h);
    __syncthreads();
    dma_tile(tr, n0 + 128, Bs0, w, lane);
    lwa0 = lw2[n0 + 128 + c]; lwb0 = lw2[n0 + 160 + c];
    compute_tile(Bs1, lwa1, lwb1, af, srun, c, h);
    __syncthreads();
    dma_tile(tr, n0 + 192, Bs1, w, lane);
    lwa1 = lw2[n0 + 192 + c]; lwb1 = lw2[n0 + 224 + c];
    compute_tile(Bs0, lwa0, lwb0, af, srun, c, h);
    __syncthreads();
    dma_tile(tr, n0 + 256, Bs0, w, lane);
    lwa0 = lw2[n0 + 256 + c]; lwb0 = lw2[n0 + 288 + c];
    compute_tile(Bs1, lwa1, lwb1, af, srun, c, h);
    __syncthreads();
    dma_tile(tr, n0 + 320, Bs1, w, lane);
    lwa1 = lw2[n0 + 320 + c]; lwb1 = lw2[n0 + 352 + c];
    compute_tile(Bs0, lwa0, lwb0, af, srun, c, h);
    __syncthreads();
    dma_tile(tr, n0 + 384, Bs0, w, lane);
    lwa0 = lw2[n0 + 384 + c]; lwb0 = lw2[n0 + 416 + c];
    compute_tile(Bs1, lwa1, lwb1, af, srun, c, h);
    __syncthreads();
    dma_tile(tr, n0 + 448, Bs1, w, lane);
    lwa1 = lw2[n0 + 448 + c]; lwb1 = lw2[n0 + 480 + c];
    compute_tile(Bs0, lwa0, lwb0, af, srun, c, h);
    __syncthreads();
    compute_tile(Bs1, lwa1, lwb1, af, srun, c, h);

    // ---- cross-lane row sum (cols live across 32 lanes) ----
    __syncthreads();
    float* red = reinterpret_cast<float*>(smem);   // 128 x 33 f32 (16896 B)
#pragma unroll
    for (int r = 0; r < 16; ++r) {
        int rowl = (r & 3) + 8 * (r >> 2) + 4 * h;
        red[(w * 32 + rowl) * 33 + c] = srun[r];
    }
    __syncthreads();
    if (tid < 128) {
        float G = 0.f;
#pragma unroll
        for (int c2 = 0; c2 < 32; ++c2) G += red[tid * 33 + c2];
        part[(size_t)chunk * M + m0 + tid] = G;   // [chunk][m] coalesced
    }
}

__global__ __launch_bounds__(256) void gk_merge(const float* __restrict__ part,
                                                const float* __restrict__ au2,
                                                const float* __restrict__ sw,
                                                float* __restrict__ out) {
    __shared__ float red[256];
    const int tid = threadIdx.x;
    // W = sum(sw), recomputed per block (64 KB, L2-resident, fully parallel)
    float s = 0.f;
    const float4* p4 = reinterpret_cast<const float4*>(sw);
    for (int i = tid; i < N / 4; i += 256) {
        float4 v = p4[i];
        s += v.x + v.y + v.z + v.w;
    }
    red[tid] = s;
    __syncthreads();
    for (int off = 128; off > 0; off >>= 1) {
        if (tid < off) red[tid] += red[tid + off];
        __syncthreads();
    }
    const float W = red[0];

    const int r = blockIdx.x * 256 + tid;
    float G = 0.f;
#pragma unroll
    for (int p = 0; p < PCH; ++p) G += part[(size_t)p * M + r];
    out[r] = LN2 * (au2[r] + __builtin_amdgcn_logf(fmaxf(G, 1e-30f)) - B0
                   - __builtin_amdgcn_logf(W)) - ZC;
}

extern "C" void kernel_launch(void* const* d_in, const int* in_sizes, int n_in,
                              void* d_out, int out_size, void* d_ws, size_t ws_size,
                              hipStream_t stream) {
    const float* testX  = (const float*)d_in[0];   // [8192, 64]
    const float* trainX = (const float*)d_in[1];   // [16384, 64]
    const float* sw     = (const float*)d_in[2];   // [16384]
    float* out = (float*)d_out;                    // [8192]
    char* wsb = (char*)d_ws;

    float* au2  = (float*)(wsb + B_AU2);
    float* lw2  = (float*)(wsb + B_LW2);
    float* part = (float*)(wsb + B_PART);
    __hip_bfloat16* tb = (__hip_bfloat16*)(wsb + B_TB);
    __hip_bfloat16* rb = (__hip_bfloat16*)(wsb + B_TR);

    gk_prep<<<M / 32 + N / 32, 256, 0, stream>>>(testX, trainX, sw, tb, rb, au2, lw2);
    gk_main<<<(M / 128) * PCH, 256, 0, stream>>>(tb, rb, lw2, part);
    gk_merge<<<M / 256, 256, 0, stream>>>(part, au2, sw, out);
}